// Round 3
// baseline (98.598 us; speedup 1.0000x reference)
//
#include <hip/hip_runtime.h>
#include <math.h>

// Tropical (min-plus) matmul: out[b,o] = min_j (x[b,j] + w[o,j])
// x: [512, 512] f32, w: [1024, 512] f32, out: [512, 1024] f32
//
// R5 post-mortem: kernel ~34us vs predicted 8-12. Three LDS-staged
// structures (R3 31.6 / R4 47 / R5 34) all land 32-47us while LDS-byte +
// VALU-issue models say 4-8us -> the bottleneck is NOT LDS bandwidth.
// Common suspects: barrier-synced stage phases (waves stall together,
// latency doesn't overlap) and, in R5, s_load/ds_read sharing lgkmcnt
// (out-of-order completion forces lgkmcnt(0) drain per chunk -> each
// chunk costs a full memory round trip).
// R6: eliminate the suspects entirely -- NO LDS, NO barriers, NO scalar
// loads. 4b x 4o register tile fed by global_load_dwordx4 out of L1/L2
// (w-tile 32KB + x-tile 32KB per block; w total 2MB is L3-resident).
// Per 4j iter: 8 dwordx4 loads (~72 TA-cyc) vs 64 VALU insts (128 cyc)
// -> VALU-bound; 32 independent iters pipeline on vmcnt only.
// Grid fix vs R4: K-split 4. 8(b) x 16(o) x 4(k) = 512 blocks, 2/CU,
// 8 waves/CU, 2/SIMD. Partial mins (8MB) -> d_ws; streaming combine
// kernel (10MB, ~1.7us) reduces 4 partials -> out.
// Predict: main ~5-8us, combine ~2us, total ~48-54us. Main kernel:
// LDS_Block_Size=0, SQ_LDS_BANK_CONFLICT=0, VALUBusy high. If it still
// lands >=25us with low VALUBusy -> bottleneck is environmental.

typedef float v2f __attribute__((ext_vector_type(2)));

#define B_     512
#define IN_    512
#define OUT_   1024
#define KSPLIT 4
#define KSEG   (IN_ / KSPLIT)   // 128 j per block
#define TBB    64               // b-rows per block
#define TOO    64               // o-rows per block

__global__ __launch_bounds__(256, 2) void tropical_main(
    const float* __restrict__ x, const float* __restrict__ w,
    float* __restrict__ part)
{
    const int tid = threadIdx.x;
    const int og  = tid & 15;        // o-group within block (16)
    const int bg  = tid >> 4;        // b-group within block (16)
    const int b0  = blockIdx.x * TBB + bg * 4;   // this lane's 4 b-rows
    const int o0  = blockIdx.y * TOO + og * 4;   // this lane's 4 o-rows
    const int k0  = blockIdx.z * KSEG;

    float acc[4][4];
#pragma unroll
    for (int i = 0; i < 4; ++i)
#pragma unroll
        for (int ii = 0; ii < 4; ++ii) acc[i][ii] = INFINITY;

    // 32 iterations, fully independent; compiler pipelines loads on vmcnt.
    // x inst: 16-lane groups share a b-row -> 4 distinct 16B reqs/inst.
    // w inst: 16 distinct rows (2KB stride) -> 16 lines/inst; the next
    // 3 iters hit the same 64B lines in L1 (75% L1 hit on w).
#pragma unroll 2
    for (int j = k0; j < k0 + KSEG; j += 4) {
        float4 xv[4], wv[4];
#pragma unroll
        for (int i = 0; i < 4; ++i)
            xv[i] = *(const float4*)&x[(size_t)(b0 + i) * IN_ + j];
#pragma unroll
        for (int i = 0; i < 4; ++i)
            wv[i] = *(const float4*)&w[(size_t)(o0 + i) * IN_ + j];

#pragma unroll
        for (int bi = 0; bi < 4; ++bi) {
            const v2f x0 = {xv[bi].x, xv[bi].y};
            const v2f x1 = {xv[bi].z, xv[bi].w};
#pragma unroll
            for (int oi = 0; oi < 4; ++oi) {
                const v2f w0 = {wv[oi].x, wv[oi].y};
                const v2f w1 = {wv[oi].z, wv[oi].w};
                v2f s;
                s = x0 + w0;  // v_pk_add_f32
                acc[bi][oi] = fminf(fminf(acc[bi][oi], s.x), s.y);  // v_min3_f32
                s = x1 + w1;
                acc[bi][oi] = fminf(fminf(acc[bi][oi], s.x), s.y);
            }
        }
    }

    // partial store: part[ks][b][o]; lanes 0..15 write consecutive f4 = 256B
    float* dst = part + (size_t)blockIdx.z * (B_ * OUT_);
#pragma unroll
    for (int i = 0; i < 4; ++i) {
        float4 v = {acc[i][0], acc[i][1], acc[i][2], acc[i][3]};
        *(float4*)&dst[(size_t)(b0 + i) * OUT_ + o0] = v;
    }
}

__global__ __launch_bounds__(256) void tropical_combine(
    const float* __restrict__ part, float* __restrict__ out)
{
    const size_t idx = ((size_t)blockIdx.x * 256 + threadIdx.x) * 4;
    const size_t N = (size_t)B_ * OUT_;
    float4 a = *(const float4*)&part[idx];
#pragma unroll
    for (int s = 1; s < KSPLIT; ++s) {
        const float4 b = *(const float4*)&part[s * N + idx];
        a.x = fminf(a.x, b.x);
        a.y = fminf(a.y, b.y);
        a.z = fminf(a.z, b.z);
        a.w = fminf(a.w, b.w);
    }
    *(float4*)&out[idx] = a;
}

extern "C" void kernel_launch(void* const* d_in, const int* in_sizes, int n_in,
                              void* d_out, int out_size, void* d_ws, size_t ws_size,
                              hipStream_t stream) {
    const float* x = (const float*)d_in[0];   // [512, 512]
    const float* w = (const float*)d_in[1];   // [1024, 512]
    float* out = (float*)d_out;               // [512, 1024]
    float* part = (float*)d_ws;               // 4 x 512 x 1024 f32 = 8 MB

    dim3 g1(B_ / TBB, OUT_ / TOO, KSPLIT);    // 8 x 16 x 4 = 512 blocks, 2/CU
    tropical_main<<<g1, 256, 0, stream>>>(x, w, part);

    const int nvec = (B_ * OUT_) / 4;         // 131072 float4s
    tropical_combine<<<dim3(nvec / 256), 256, 0, stream>>>(part, out);
}

// Round 4
// 75.495 us; speedup vs baseline: 1.3060x; 1.3060x over previous
//
#include <hip/hip_runtime.h>
#include <math.h>

// Tropical (min-plus) matmul: out[b,o] = min_j (x[b,j] + w[o,j])
// x: [512, 512] f32, w: [1024, 512] f32, out: [512, 1024] f32
//
// R6 post-mortem (first run with kernel-attributed counters): no-LDS
// gather kernel = 42us, VALUBusy 15%, HBM 5% -> pure latency-bound.
// w-loads touch 16 cache lines/inst (private o-rows, 2KB stride) and the
// harness's 268MB poison fill leaves caches cold, so each batch is a
// serialized ~400-900cy round trip (48 VGPRs -> ~2 batches in flight).
// R3 (31.6us) actually MATCHED its LDS model (20.5 LDS + 5 issue + stage).
// R7 = R6's K-split grid (4x4 tile yet 512 blocks) + R3's staging:
//   - block = 64b x 64o x 128j brick; KSPLIT=4 -> grid 8x16x4 = 512
//     blocks, 2/CU, 8 waves/CU (R4 lesson: never below 2 waves/SIMD).
//   - stage x-tile+w-tile (64KB) via 16 coalesced f4 loads/thread,
//     16-deep MLP hides cold-HBM latency; ONE barrier total.
//   - inner: 32 iters x (8 ds_read_b128 w/ compile-time imm offsets +
//     64 VALU @ 1 inst/MAC pk_add+min3). Zero inner addr math (R5
//     lesson: no s_load/lgkmcnt coupling; padded rows not swizzle).
//   - PADW=132: row stride %32 = 4 banks. x-reads broadcast (16-lane
//     same-addr), w-reads 2-way (og vs og+8) = free per m136.
//   - LDS traffic 2 B/MAC -> 2048 b128-reads/CU x ~12cy = 10.2us floor.
//   - partials (4x512x1024 f32 = 8MB) -> d_ws; combine kernel mins 4.
// Predict: main 11-15us (VALUBusy 30-45%, conflicts ~0), combine ~3us,
// total ~56-63us. If main >=25us with low VALUBusy -> environmental cap,
// revert to best-known and stop.

typedef float v2f __attribute__((ext_vector_type(2)));

#define B_     512
#define IN_    512
#define OUT_   1024
#define KSPLIT 4
#define KSEG   (IN_ / KSPLIT)   // 128 j per block
#define TBB    64               // b rows per block
#define TOO    64               // o rows per block
#define PADW   132              // floats per LDS row; 528B, %16==0, %32f==4

__global__ __launch_bounds__(256, 2) void tropical_main(
    const float* __restrict__ x, const float* __restrict__ w,
    float* __restrict__ part)
{
    __shared__ float xs[TBB * PADW];   // 33.8 KB
    __shared__ float ws[TOO * PADW];   // 33.8 KB  (67.6 KB total, 2/CU ok)

    const int tid = threadIdx.x;
    const int b0  = blockIdx.x * TBB;
    const int o0  = blockIdx.y * TOO;
    const int k0  = blockIdx.z * KSEG;

    // ---- stage both tiles: 64 rows x 32 f4-cols each; 8 f4/thread/tile ----
    {
        const int c4 = tid & 31;   // f4 col 0..31
        const int r0 = tid >> 5;   // row slot 0..7
        float4 xv[8], wv[8];
#pragma unroll
        for (int p = 0; p < 8; ++p) {
            const int r = r0 + 8 * p;
            xv[p] = *(const float4*)&x[(size_t)(b0 + r) * IN_ + k0 + c4 * 4];
            wv[p] = *(const float4*)&w[(size_t)(o0 + r) * IN_ + k0 + c4 * 4];
        }
#pragma unroll
        for (int p = 0; p < 8; ++p) {
            const int r = r0 + 8 * p;
            *(float4*)&xs[r * PADW + c4 * 4] = xv[p];
            *(float4*)&ws[r * PADW + c4 * 4] = wv[p];
        }
    }
    __syncthreads();   // the ONLY barrier

    // ---- compute: 4x4 strided register tile ----
    const int og = tid & 15;    // o rows: og + 16*ii
    const int bg = tid >> 4;    // b rows: bg + 16*i

    const float* xr0 = &xs[(bg +  0) * PADW];
    const float* xr1 = &xs[(bg + 16) * PADW];
    const float* xr2 = &xs[(bg + 32) * PADW];
    const float* xr3 = &xs[(bg + 48) * PADW];
    const float* wr0 = &ws[(og +  0) * PADW];
    const float* wr1 = &ws[(og + 16) * PADW];
    const float* wr2 = &ws[(og + 32) * PADW];
    const float* wr3 = &ws[(og + 48) * PADW];

    float acc[4][4];
#pragma unroll
    for (int i = 0; i < 4; ++i)
#pragma unroll
        for (int ii = 0; ii < 4; ++ii) acc[i][ii] = INFINITY;

#pragma unroll 4
    for (int j = 0; j < KSEG; j += 4) {
        float4 xv[4], wv[4];
        xv[0] = *(const float4*)&xr0[j];
        xv[1] = *(const float4*)&xr1[j];
        xv[2] = *(const float4*)&xr2[j];
        xv[3] = *(const float4*)&xr3[j];
        wv[0] = *(const float4*)&wr0[j];
        wv[1] = *(const float4*)&wr1[j];
        wv[2] = *(const float4*)&wr2[j];
        wv[3] = *(const float4*)&wr3[j];

#pragma unroll
        for (int bi = 0; bi < 4; ++bi) {
            const v2f x0 = {xv[bi].x, xv[bi].y};
            const v2f x1 = {xv[bi].z, xv[bi].w};
#pragma unroll
            for (int oi = 0; oi < 4; ++oi) {
                const v2f w0 = {wv[oi].x, wv[oi].y};
                const v2f w1 = {wv[oi].z, wv[oi].w};
                v2f s;
                s = x0 + w0;  // v_pk_add_f32
                acc[bi][oi] = fminf(fminf(acc[bi][oi], s.x), s.y);  // v_min3_f32
                s = x1 + w1;
                acc[bi][oi] = fminf(fminf(acc[bi][oi], s.x), s.y);
            }
        }
    }

    // ---- store partials: 16 scalar stores, 16-lane groups -> 64B segs ----
    float* dst = part + (size_t)blockIdx.z * (B_ * OUT_);
#pragma unroll
    for (int i = 0; i < 4; ++i)
#pragma unroll
        for (int ii = 0; ii < 4; ++ii)
            dst[(size_t)(b0 + bg + 16 * i) * OUT_ + o0 + og + 16 * ii] = acc[i][ii];
}

__global__ __launch_bounds__(256) void tropical_combine(
    const float* __restrict__ part, float* __restrict__ out)
{
    const size_t idx = ((size_t)blockIdx.x * 256 + threadIdx.x) * 4;
    const size_t N = (size_t)B_ * OUT_;
    float4 a = *(const float4*)&part[idx];
#pragma unroll
    for (int s = 1; s < KSPLIT; ++s) {
        const float4 b = *(const float4*)&part[s * N + idx];
        a.x = fminf(a.x, b.x);
        a.y = fminf(a.y, b.y);
        a.z = fminf(a.z, b.z);
        a.w = fminf(a.w, b.w);
    }
    *(float4*)&out[idx] = a;
}

extern "C" void kernel_launch(void* const* d_in, const int* in_sizes, int n_in,
                              void* d_out, int out_size, void* d_ws, size_t ws_size,
                              hipStream_t stream) {
    const float* x = (const float*)d_in[0];   // [512, 512]
    const float* w = (const float*)d_in[1];   // [1024, 512]
    float* out = (float*)d_out;               // [512, 1024]
    float* part = (float*)d_ws;               // 4 x 512 x 1024 f32 = 8 MB

    dim3 g1(B_ / TBB, OUT_ / TOO, KSPLIT);    // 8 x 16 x 4 = 512 blocks, 2/CU
    tropical_main<<<g1, 256, 0, stream>>>(x, w, part);

    const int nvec = (B_ * OUT_) / 4;         // 131072 float4s
    tropical_combine<<<dim3(nvec / 256), 256, 0, stream>>>(part, out);
}

// Round 5
// 74.168 us; speedup vs baseline: 1.3294x; 1.0179x over previous
//
#include <hip/hip_runtime.h>
#include <math.h>

// Tropical (min-plus) matmul: out[b,o] = min_j (x[b,j] + w[o,j])
// x: [512, 512] f32, w: [1024, 512] f32, out: [512, 1024] f32
//
// R7 post-mortem: main+combine ~34.5us, no better than R3's 31.6. The R6
// calibration point (VALU-active 15% x 43us = 6.45us == inst-count model
// at 2.4GHz) proves clocks are full and ~85% of time is memory-latency
// stall in EVERY variant. All variants ran 2 waves/SIMD (2 blocks/CU):
// nothing to execute during barrier drains / stage phases / lgkmcnt
// waits. The bottleneck is TLP, not LDS bytes, not VALU insts.
// R8: 32 waves/CU (8/SIMD, chip max).
//   waves/CU = 524288*KSPLIT/(64*P*256); P=4 (2x2 tile), KSPLIT=4
//   -> grid 16x32x4 = 2048 blocks of 256, 8 blocks/CU.
//   - LDS/block must be <=20KB: BK=64 staging -> (32+32)x68x4B = 17.4KB.
//   - VGPR <= 64 required for 8 waves/SIMD: __launch_bounds__(256,8);
//     2x2 tile needs ~45.
//   - Keep all proven pieces: 1 inst/MAC (v_pk_add_f32 + v_min3_f32),
//     compile-time-offset ds_reads, strided row ownership (x reads
//     broadcast across 16 lanes = free; w reads 2-way = free, PADW=68
//     row stride %32f = 4 banks), coalesced f4 staging, no lgkmcnt
//     coupling (no s_load in loop).
//   - 8 independent blocks/CU overlap each other's barriers and stage
//     latency -- the architectural fix for the 85% stall.
// Floors: VALU 3.4us, LDS service ~2.6us, L3 staging 64MB ~5-6us, all
// overlapped. Predict main 8-14us, combine ~3us, total ~55-63us.
// Falsification: total >= 70us -> TLP theory wrong, revert to best-known.

typedef float v2f __attribute__((ext_vector_type(2)));

#define B_     512
#define IN_    512
#define OUT_   1024
#define KSPLIT 4
#define KSEG   (IN_ / KSPLIT)   // 128 j per block
#define BK     64               // j staged per step (2 steps per block)
#define TB     32               // b rows per block
#define TO     32               // o rows per block
#define PADW   68               // floats per LDS row: 272B, %16==0, %32f==4

__global__ __launch_bounds__(256, 8) void tropical_main(
    const float* __restrict__ x, const float* __restrict__ w,
    float* __restrict__ part)
{
    __shared__ float xs[TB * PADW];   // 8.7 KB
    __shared__ float ws[TO * PADW];   // 8.7 KB   (17.4 KB total -> 8 blocks/CU)

    const int tid = threadIdx.x;
    const int b0  = blockIdx.x * TB;
    const int o0  = blockIdx.y * TO;
    const int k0  = blockIdx.z * KSEG;

    // staging coords: tile = 32 rows x 16 f4-cols; 256 thr = 2 rows/thread
    const int c4 = tid & 15;    // f4 col 0..15
    const int sr = tid >> 4;    // row 0..15 (+16 second row)

    // compute coords: 2x2 strided tile; x rows tb,tb+16; w rows to,to+16
    const int to = tid & 15;
    const int tb = tid >> 4;

    float acc00 = INFINITY, acc01 = INFINITY;
    float acc10 = INFINITY, acc11 = INFINITY;

    for (int ks = 0; ks < KSEG; ks += BK) {
        // ---- stage x/w 32x64 tiles (2 f4 each per thread, coalesced) ----
        {
            const float4 xv0 = *(const float4*)&x[(size_t)(b0 + sr) * IN_ + k0 + ks + c4 * 4];
            const float4 xv1 = *(const float4*)&x[(size_t)(b0 + sr + 16) * IN_ + k0 + ks + c4 * 4];
            const float4 wv0 = *(const float4*)&w[(size_t)(o0 + sr) * IN_ + k0 + ks + c4 * 4];
            const float4 wv1 = *(const float4*)&w[(size_t)(o0 + sr + 16) * IN_ + k0 + ks + c4 * 4];
            *(float4*)&xs[sr * PADW + c4 * 4] = xv0;
            *(float4*)&xs[(sr + 16) * PADW + c4 * 4] = xv1;
            *(float4*)&ws[sr * PADW + c4 * 4] = wv0;
            *(float4*)&ws[(sr + 16) * PADW + c4 * 4] = wv1;
        }
        __syncthreads();

        const float* xr0 = &xs[tb * PADW];
        const float* xr1 = &xs[(tb + 16) * PADW];
        const float* wr0 = &ws[to * PADW];
        const float* wr1 = &ws[(to + 16) * PADW];

        // ---- inner: per 4j, 4 ds_read_b128 + 16 VALU (1 inst/MAC) ----
#pragma unroll 4
        for (int j = 0; j < BK; j += 4) {
            const float4 xa = *(const float4*)&xr0[j];
            const float4 xb = *(const float4*)&xr1[j];
            const float4 wa = *(const float4*)&wr0[j];
            const float4 wb = *(const float4*)&wr1[j];
            const v2f xa0 = {xa.x, xa.y}, xa1 = {xa.z, xa.w};
            const v2f xb0 = {xb.x, xb.y}, xb1 = {xb.z, xb.w};
            const v2f wa0 = {wa.x, wa.y}, wa1 = {wa.z, wa.w};
            const v2f wb0 = {wb.x, wb.y}, wb1 = {wb.z, wb.w};
            v2f t;
            t = xa0 + wa0; acc00 = fminf(fminf(acc00, t.x), t.y);
            t = xa1 + wa1; acc00 = fminf(fminf(acc00, t.x), t.y);
            t = xa0 + wb0; acc01 = fminf(fminf(acc01, t.x), t.y);
            t = xa1 + wb1; acc01 = fminf(fminf(acc01, t.x), t.y);
            t = xb0 + wa0; acc10 = fminf(fminf(acc10, t.x), t.y);
            t = xb1 + wa1; acc10 = fminf(fminf(acc10, t.x), t.y);
            t = xb0 + wb0; acc11 = fminf(fminf(acc11, t.x), t.y);
            t = xb1 + wb1; acc11 = fminf(fminf(acc11, t.x), t.y);
        }
        __syncthreads();
    }

    // ---- store partials: 4 scalar stores, 16-lane groups -> 64B segs ----
    float* dst = part + (size_t)blockIdx.z * (B_ * OUT_);
    dst[(size_t)(b0 + tb) * OUT_ + o0 + to]            = acc00;
    dst[(size_t)(b0 + tb) * OUT_ + o0 + to + 16]       = acc01;
    dst[(size_t)(b0 + tb + 16) * OUT_ + o0 + to]       = acc10;
    dst[(size_t)(b0 + tb + 16) * OUT_ + o0 + to + 16]  = acc11;
}

__global__ __launch_bounds__(256) void tropical_combine(
    const float* __restrict__ part, float* __restrict__ out)
{
    const size_t idx = ((size_t)blockIdx.x * 256 + threadIdx.x) * 4;
    const size_t N = (size_t)B_ * OUT_;
    float4 a = *(const float4*)&part[idx];
#pragma unroll
    for (int s = 1; s < KSPLIT; ++s) {
        const float4 b = *(const float4*)&part[s * N + idx];
        a.x = fminf(a.x, b.x);
        a.y = fminf(a.y, b.y);
        a.z = fminf(a.z, b.z);
        a.w = fminf(a.w, b.w);
    }
    *(float4*)&out[idx] = a;
}

extern "C" void kernel_launch(void* const* d_in, const int* in_sizes, int n_in,
                              void* d_out, int out_size, void* d_ws, size_t ws_size,
                              hipStream_t stream) {
    const float* x = (const float*)d_in[0];   // [512, 512]
    const float* w = (const float*)d_in[1];   // [1024, 512]
    float* out = (float*)d_out;               // [512, 1024]
    float* part = (float*)d_ws;               // 4 x 512 x 1024 f32 = 8 MB

    dim3 g1(B_ / TB, OUT_ / TO, KSPLIT);      // 16 x 32 x 4 = 2048 blocks, 8/CU
    tropical_main<<<g1, 256, 0, stream>>>(x, w, part);

    const int nvec = (B_ * OUT_) / 4;         // 131072 float4s
    tropical_combine<<<dim3(nvec / 256), 256, 0, stream>>>(part, out);
}